// Round 9
// baseline (127.860 us; speedup 1.0000x reference)
//
#include <hip/hip_runtime.h>
#include <hip/hip_bf16.h>
#include <stdint.h>

#define NROWS 8192
#define BROWS 4096
#define SQRT_SCALE 3.7982826f   // sqrt((1/T)*log2(e)), T=0.1
#define LN2 0.6931471805599453f
#define NBLK 544                // sum_{it=0}^{63} ceil((8192-128it)/512), = 8*68

typedef __attribute__((ext_vector_type(8))) short bf16x8;
typedef __attribute__((ext_vector_type(4))) float f32x4;

__device__ inline void gload_lds16(const void* g, void* l) {
  __builtin_amdgcn_global_load_lds((const __attribute__((address_space(1))) void*)g,
                                   (__attribute__((address_space(3))) void*)l,
                                   16, 0, 0);
}

__device__ inline unsigned short f2bf(float x) {
  __hip_bfloat16 h = __float2bfloat16(x);
  return __builtin_bit_cast(unsigned short, h);
}

// Kernel A: L2-normalize rows, scale by sqrt((1/T)log2e), -> bf16 reps; zero denom/out.
__global__ __launch_bounds__(256) void knorm(const float* __restrict__ zi,
                                             const float* __restrict__ zj,
                                             unsigned short* __restrict__ reps,
                                             float* __restrict__ denom,
                                             float* __restrict__ out) {
  int w = threadIdx.x >> 6, l = threadIdx.x & 63;
  int row = blockIdx.x * 4 + w;
  const float* src = (row < BROWS) ? (zi + (size_t)row * 256)
                                   : (zj + (size_t)(row - BROWS) * 256);
  float4 v = ((const float4*)src)[l];
  float ss = v.x * v.x + v.y * v.y + v.z * v.z + v.w * v.w;
#pragma unroll
  for (int m = 1; m < 64; m <<= 1) ss += __shfl_xor(ss, m, 64);
  float sc = SQRT_SCALE / fmaxf(sqrtf(ss), 1e-12f);
  ushort4 o;
  o.x = f2bf(v.x * sc); o.y = f2bf(v.y * sc);
  o.z = f2bf(v.z * sc); o.w = f2bf(v.w * sc);
  ((ushort4*)reps)[(size_t)row * 64 + l] = o;
  if (l == 0) denom[row] = 0.f;
  if (row == 0 && l == 0) out[0] = 0.f;
}

// Kernel B: strip-streaming upper-tri sim. Wave = 64 rows x 32 cols; 64-col
// LDS tiles (32KB, double-buffered); 64 MFMA : 16 ds_read per iter per wave;
// ONE barrier/iter; epilogue ping-pong overlapped with next tile's MFMA.
// Block = (128-row strip it, 512-col chunk q); XCD-swizzled blockIdx.
__global__ __launch_bounds__(256, 2) void ksim(const unsigned short* __restrict__ reps_,
                                               float* __restrict__ denom,
                                               float* __restrict__ pos) {
  __shared__ uint4 smem[2][2048];    // 2 x 64 rows x 512 B = 64 KB
  __shared__ float colacc[512];
  const uint4* reps4 = (const uint4*)reps_;
  int tid = threadIdx.x, w = tid >> 6, l = tid & 63;
  int wr = w >> 1, wc = w & 1;       // wave = rows [wr*64,+64) x cols [wc*32,+32)
  int kgrp = l >> 4;

  // ---- XCD swizzle (544 = 8*68, bijective) + block -> (strip it, chunk q) ----
  int b = blockIdx.x;
  int orig = (b & 7) * 68 + (b >> 3);
  int rem = orig, it = 0, ch;
  while (rem >= (ch = (NROWS - 128 * it + 511) >> 9)) { rem -= ch; ++it; }
  int q = rem;
  int rowbase = it * 128;
  int cs0 = rowbase + q * 512;
  int len = NROWS - cs0; if (len > 512) len = 512;
  int ntile = len >> 6;              // even: 2,4,6,8

  for (int o = tid; o < 512; o += 256) colacc[o] = 0.f;

  // ---- staging: 64 reps-rows x 512B -> 32KB buffer; linear dest, swizzled src ----
  auto stage = [&](int bufi, int colbase) {
#pragma unroll
    for (int i = 0; i < 8; ++i) {
      int c2 = w * 8 + i;            // 32 chunks of 1 KB (2 rows each)
      int lr = 2 * c2 + (l >> 5);
      int kb = ((l & 31) * 16) ^ ((lr & 7) << 4);
      gload_lds16((const char*)reps_ + (size_t)(colbase + lr) * 512 + kb,
                  (void*)&smem[bufi][c2 * 64]);
    }
  };
  stage(0, cs0);

  // ---- A fragments: lane holds row rowbase+wr*64+fr*16+(l&15), 16B chunk kgrp ----
  bf16x8 a[4][8];
  int arow = rowbase + wr * 64 + (l & 15);
#pragma unroll
  for (int fr = 0; fr < 4; ++fr) {
    const uint4* base = reps4 + (size_t)(arow + fr * 16) * 32 + kgrp;
#pragma unroll
    for (int kk = 0; kk < 8; ++kk)
      a[fr][kk] = __builtin_bit_cast(bf16x8, base[kk * 4]);
  }

  // ---- precomputed per-kk LDS byte offsets; row+16 is a constant +8192 ----
  int lds_a[8];
  {
    int lr0 = wc * 32 + (l & 15);
    int swz = (lr0 & 7) << 4;
#pragma unroll
    for (int kk = 0; kk < 8; ++kk)
      lds_a[kk] = lr0 * 512 + ((kk * 64 + kgrp * 16) ^ swz);
  }

  float rowsum[4][4];
#pragma unroll
  for (int fr = 0; fr < 4; ++fr)
#pragma unroll
    for (int r = 0; r < 4; ++r) rowsum[fr][r] = 0.f;

  int r0 = rowbase + wr * 64 + kgrp * 4;

  // ---- epilogue on a finished acc set (regs + LDS-atomic colacc) ----
  auto epi = [&](f32x4 (&acc)[4][2], int t) {
    int cb = cs0 + 64 * t;
    bool docol = !(q == 0 && t < 2);        // diag 128-col window: rowsum only
    bool dopos = (q == 8) && (t < 2);
    float cp0 = 0.f, cp1 = 0.f;
    int cbase = cb + wc * 32 + (l & 15);
#pragma unroll
    for (int fr = 0; fr < 4; ++fr)
#pragma unroll
      for (int fc = 0; fc < 2; ++fc)
#pragma unroll
        for (int r = 0; r < 4; ++r) {
          int rg = r0 + fr * 16 + r;
          int cg = cbase + fc * 16;
          float s = acc[fr][fc][r];
          float e = __builtin_amdgcn_exp2f(s);
          e = (rg == cg) ? 0.f : e;
          if (dopos && cg == rg + BROWS) pos[rg] = s;
          rowsum[fr][r] += e;
          if (fc == 0) cp0 += e; else cp1 += e;
        }
    if (docol) {
      cp0 += __shfl_xor(cp0, 16, 64); cp0 += __shfl_xor(cp0, 32, 64);
      cp1 += __shfl_xor(cp1, 16, 64); cp1 += __shfl_xor(cp1, 32, 64);
      if (l < 16) {
        int off = (cb - cs0) + wc * 32 + l;
        atomicAdd(&colacc[off], cp0);
        atomicAdd(&colacc[off + 16], cp1);
      }
    }
  };

  int buf = 0;
  // ---- one step: wait stage(t) -> barrier -> issue stage(t+1) -> 64 MFMA
  //      -> epilogue of prev tile (overlaps MFMA shadow) ----
  auto step = [&](int t, f32x4 (&cur)[4][2], f32x4 (&prv)[4][2], bool doPrev) {
    asm volatile("s_waitcnt vmcnt(0)" ::: "memory");   // stage(t): issued 1 iter ago
    __builtin_amdgcn_sched_barrier(0);
    __builtin_amdgcn_s_barrier();                      // all waves' stage(t) landed;
    __builtin_amdgcn_sched_barrier(0);                 // all reads of buf^1 done
    if (t + 1 < ntile) stage(buf ^ 1, cs0 + 64 * (t + 1));
    const char* bb = (const char*)&smem[0][0] + buf * 32768;
    const f32x4 zero = {0.f, 0.f, 0.f, 0.f};
    __builtin_amdgcn_s_setprio(1);
#pragma unroll
    for (int kk = 0; kk < 8; ++kk) {
      bf16x8 b0 = *(const bf16x8*)(bb + lds_a[kk]);
      bf16x8 b1 = *(const bf16x8*)(bb + lds_a[kk] + 8192);  // row +16, same swizzle
#pragma unroll
      for (int fr = 0; fr < 4; ++fr) {
        if (kk == 0) {
          cur[fr][0] = __builtin_amdgcn_mfma_f32_16x16x32_bf16(a[fr][0], b0, zero, 0, 0, 0);
          cur[fr][1] = __builtin_amdgcn_mfma_f32_16x16x32_bf16(a[fr][0], b1, zero, 0, 0, 0);
        } else {
          cur[fr][0] = __builtin_amdgcn_mfma_f32_16x16x32_bf16(a[fr][kk], b0, cur[fr][0], 0, 0, 0);
          cur[fr][1] = __builtin_amdgcn_mfma_f32_16x16x32_bf16(a[fr][kk], b1, cur[fr][1], 0, 0, 0);
        }
      }
    }
    __builtin_amdgcn_s_setprio(0);
    if (doPrev) epi(prv, t - 1);
    buf ^= 1;
  };

  f32x4 accA[4][2], accB[4][2];
  for (int t = 0; t < ntile; t += 2) {     // ntile always even
    step(t,     accA, accB, t > 0);
    step(t + 1, accB, accA, true);
  }
  epi(accB, ntile - 1);

  // ---- row sums: reduce 16 col-lanes; 4 lanes atomic per wave ----
#pragma unroll
  for (int fr = 0; fr < 4; ++fr)
#pragma unroll
    for (int r = 0; r < 4; ++r) {
      float v = rowsum[fr][r];
      v += __shfl_xor(v, 1, 64);
      v += __shfl_xor(v, 2, 64);
      v += __shfl_xor(v, 4, 64);
      v += __shfl_xor(v, 8, 64);
      if ((l & 15) == 0) atomicAdd(&denom[r0 + fr * 16 + r], v);
    }

  // ---- col sums: flush colacc, one atomic per column ----
  __syncthreads();
  for (int off = tid; off < 512; off += 256) {
    float v = colacc[off];
    int col = cs0 + off;
    if (col < NROWS && v != 0.f) atomicAdd(&denom[col], v);
  }
}

// Kernel F: + (1/N) * sum_i (log(denom_i) - posS_{i mod B} * ln2)
__global__ __launch_bounds__(256) void kfin(const float* __restrict__ denom,
                                            const float* __restrict__ pos,
                                            float* __restrict__ out) {
  int i = blockIdx.x * 256 + threadIdx.x;
  float v = (logf(denom[i]) - pos[i & 4095] * LN2) * (1.0f / 8192.0f);
#pragma unroll
  for (int m = 1; m < 64; m <<= 1) v += __shfl_xor(v, m, 64);
  __shared__ float part[4];
  if ((threadIdx.x & 63) == 0) part[threadIdx.x >> 6] = v;
  __syncthreads();
  if (threadIdx.x == 0)
    atomicAdd(out, part[0] + part[1] + part[2] + part[3]);
}

extern "C" void kernel_launch(void* const* d_in, const int* in_sizes, int n_in,
                              void* d_out, int out_size, void* d_ws, size_t ws_size,
                              hipStream_t stream) {
  (void)in_sizes; (void)n_in; (void)out_size; (void)ws_size;
  const float* zi = (const float*)d_in[0];
  const float* zj = (const float*)d_in[1];
  float* out = (float*)d_out;
  char* ws = (char*)d_ws;
  unsigned short* reps = (unsigned short*)ws;                 // 4 MB
  float* denom = (float*)(ws + 4194304);                      // 32 KB
  float* pos   = (float*)(ws + 4194304 + 32768);              // 16 KB

  knorm<<<2048, 256, 0, stream>>>(zi, zj, reps, denom, out);
  ksim<<<NBLK, 256, 0, stream>>>(reps, denom, pos);
  kfin<<<32, 256, 0, stream>>>(denom, pos, out);
}

// Round 10
// 62.858 us; speedup vs baseline: 2.0341x; 2.0341x over previous
//
#include <hip/hip_runtime.h>
#include <hip/hip_bf16.h>
#include <stdint.h>

#define NROWS 8192
#define BROWS 4096
#define SQRT_SCALE 3.7982826f   // sqrt((1/T)*log2(e)), T=0.1
#define LN2 0.6931471805599453f
#define NBLK 544                // sum_{it=0}^{63} ceil((64-it)/4) = 8*68

typedef __attribute__((ext_vector_type(8))) short bf16x8;
typedef __attribute__((ext_vector_type(4))) float f32x4;

__device__ inline void gload_lds16(const void* g, void* l) {
  __builtin_amdgcn_global_load_lds((const __attribute__((address_space(1))) void*)g,
                                   (__attribute__((address_space(3))) void*)l,
                                   16, 0, 0);
}

__device__ inline unsigned short f2bf(float x) {
  __hip_bfloat16 h = __float2bfloat16(x);
  return __builtin_bit_cast(unsigned short, h);
}

// Kernel A: L2-normalize rows, scale by sqrt((1/T)log2e), -> bf16 reps; zero denom/out.
__global__ __launch_bounds__(256) void knorm(const float* __restrict__ zi,
                                             const float* __restrict__ zj,
                                             unsigned short* __restrict__ reps,
                                             float* __restrict__ denom,
                                             float* __restrict__ out) {
  int w = threadIdx.x >> 6, l = threadIdx.x & 63;
  int row = blockIdx.x * 4 + w;
  const float* src = (row < BROWS) ? (zi + (size_t)row * 256)
                                   : (zj + (size_t)(row - BROWS) * 256);
  float4 v = ((const float4*)src)[l];
  float ss = v.x * v.x + v.y * v.y + v.z * v.z + v.w * v.w;
#pragma unroll
  for (int m = 1; m < 64; m <<= 1) ss += __shfl_xor(ss, m, 64);
  float sc = SQRT_SCALE / fmaxf(sqrtf(ss), 1e-12f);
  ushort4 o;
  o.x = f2bf(v.x * sc); o.y = f2bf(v.y * sc);
  o.z = f2bf(v.z * sc); o.w = f2bf(v.w * sc);
  ((ushort4*)reps)[(size_t)row * 64 + l] = o;
  if (l == 0) denom[row] = 0.f;
  if (row == 0 && l == 0) out[0] = 0.f;
}

// Kernel B: upper-tri sim with R2's proven core: wave = 64 rows x 32 cols,
// a[4][8] A-frags, SINGLE acc[4][2], 64-col dbuf LDS tiles; 64 MFMA : 16
// ds_read per iter per wave (4:1). One barrier/iter, early stage issue,
// in-loop epilogue (exp2 + rowsum regs + colsum LDS atomics).
// Block = (128-row strip it, 512-col chunk q), XCD-swizzled.
__global__ __launch_bounds__(256, 2) void ksim(const unsigned short* __restrict__ reps_,
                                               float* __restrict__ denom,
                                               float* __restrict__ pos) {
  __shared__ uint4 smem[2][2048];    // 2 x 64 reps-rows x 512 B = 64 KB
  __shared__ float colacc[512];      // 2 KB
  const uint4* reps4 = (const uint4*)reps_;
  int tid = threadIdx.x, w = tid >> 6, l = tid & 63;
  int wr = w >> 1, wc = w & 1;       // wave = rows [wr*64,+64) x cols [wc*32,+32)
  int kgrp = l >> 4;

  // ---- XCD swizzle (544 = 8*68, bijective) + block -> (strip it, chunk q) ----
  int b = blockIdx.x;
  int orig = (b & 7) * 68 + (b >> 3);
  int rem = orig, it = 0, ch;
  while (rem >= (ch = (64 - it + 3) >> 2)) { rem -= ch; ++it; }
  int q = rem;
  int rowbase = it * 128;
  int cs0 = rowbase + q * 512;
  int len = NROWS - cs0; if (len > 512) len = 512;
  int ntile = len >> 6;              // 2,4,6,8 (len is a multiple of 128)

  colacc[tid] = 0.f; colacc[tid + 256] = 0.f;

  // ---- staging: 64 reps-rows x 512B -> 32KB buffer; linear dest, swizzled src ----
  auto stage = [&](int bufi, int colbase) {
#pragma unroll
    for (int i = 0; i < 8; ++i) {
      int c2 = w * 8 + i;            // 32 chunks of 1 KB (2 rows each)
      int lr = 2 * c2 + (l >> 5);
      int kb = ((l & 31) * 16) ^ ((lr & 7) << 4);
      gload_lds16((const char*)reps_ + (size_t)(colbase + lr) * 512 + kb,
                  (void*)&smem[bufi][c2 * 64]);
    }
  };
  stage(0, cs0);

  // ---- A fragments: lane holds row rowbase+wr*64+fr*16+(l&15), 16B chunk kgrp ----
  bf16x8 a[4][8];
  int arow = rowbase + wr * 64 + (l & 15);
#pragma unroll
  for (int fr = 0; fr < 4; ++fr) {
    const uint4* base = reps4 + (size_t)(arow + fr * 16) * 32 + kgrp;
#pragma unroll
    for (int kk = 0; kk < 8; ++kk)
      a[fr][kk] = __builtin_bit_cast(bf16x8, base[kk * 4]);
  }

  // ---- precomputed per-kk LDS byte offsets; col+16 is +8192 (same swizzle) ----
  int lds_a[8];
  {
    int lr0 = wc * 32 + (l & 15);
    int swz = (lr0 & 7) << 4;
#pragma unroll
    for (int kk = 0; kk < 8; ++kk)
      lds_a[kk] = lr0 * 512 + ((kk * 64 + kgrp * 16) ^ swz);
  }

  float rowsum[4][4];
#pragma unroll
  for (int fr = 0; fr < 4; ++fr)
#pragma unroll
    for (int r = 0; r < 4; ++r) rowsum[fr][r] = 0.f;

  int r0 = rowbase + wr * 64 + kgrp * 4;
  int buf = 0;

  for (int t = 0; t < ntile; ++t) {
    // stage(t) was issued one full compute phase ago -> wait is covered
    asm volatile("s_waitcnt vmcnt(0)" ::: "memory");
    __builtin_amdgcn_sched_barrier(0);
    __builtin_amdgcn_s_barrier();      // stage(t) visible; buf^1 reads all done
    __builtin_amdgcn_sched_barrier(0);
    if (t + 1 < ntile) stage(buf ^ 1, cs0 + 64 * (t + 1));

    const char* bb = (const char*)&smem[0][0] + buf * 32768;
    f32x4 acc[4][2];
    const f32x4 zero = {0.f, 0.f, 0.f, 0.f};
    __builtin_amdgcn_s_setprio(1);
#pragma unroll
    for (int kk = 0; kk < 8; ++kk) {
      bf16x8 b0 = *(const bf16x8*)(bb + lds_a[kk]);
      bf16x8 b1 = *(const bf16x8*)(bb + lds_a[kk] + 8192);
#pragma unroll
      for (int fr = 0; fr < 4; ++fr) {
        if (kk == 0) {
          acc[fr][0] = __builtin_amdgcn_mfma_f32_16x16x32_bf16(a[fr][0], b0, zero, 0, 0, 0);
          acc[fr][1] = __builtin_amdgcn_mfma_f32_16x16x32_bf16(a[fr][0], b1, zero, 0, 0, 0);
        } else {
          acc[fr][0] = __builtin_amdgcn_mfma_f32_16x16x32_bf16(a[fr][kk], b0, acc[fr][0], 0, 0, 0);
          acc[fr][1] = __builtin_amdgcn_mfma_f32_16x16x32_bf16(a[fr][kk], b1, acc[fr][1], 0, 0, 0);
        }
      }
    }
    __builtin_amdgcn_s_setprio(0);

    // ---- epilogue: e=exp2(acc), diag mask, rowsum + col partials ----
    int cb = cs0 + 64 * t;
    bool docol = !(q == 0 && t < 2);        // diag 128-col window: rowsum only
    bool dopos = (q == 8) && (t < 2) && (it < 32);
    float cp0 = 0.f, cp1 = 0.f;
    int cbase = cb + wc * 32 + (l & 15);
#pragma unroll
    for (int fr = 0; fr < 4; ++fr)
#pragma unroll
      for (int fc = 0; fc < 2; ++fc)
#pragma unroll
        for (int r = 0; r < 4; ++r) {
          int rg = r0 + fr * 16 + r;
          int cg = cbase + fc * 16;
          float s = acc[fr][fc][r];
          float e = __builtin_amdgcn_exp2f(s);
          e = (rg == cg) ? 0.f : e;
          if (dopos && cg == rg + BROWS) pos[rg] = s;
          rowsum[fr][r] += e;
          if (fc == 0) cp0 += e; else cp1 += e;
        }
    if (docol) {
      cp0 += __shfl_xor(cp0, 16, 64); cp0 += __shfl_xor(cp0, 32, 64);
      cp1 += __shfl_xor(cp1, 16, 64); cp1 += __shfl_xor(cp1, 32, 64);
      if (l < 16) {
        int off = (cb - cs0) + wc * 32 + l;
        atomicAdd(&colacc[off], cp0);
        atomicAdd(&colacc[off + 16], cp1);
      }
    }
    buf ^= 1;
  }

  // ---- row sums: reduce 16 col-lanes; 4 lanes atomic per wave ----
#pragma unroll
  for (int fr = 0; fr < 4; ++fr)
#pragma unroll
    for (int r = 0; r < 4; ++r) {
      float v = rowsum[fr][r];
      v += __shfl_xor(v, 1, 64);
      v += __shfl_xor(v, 2, 64);
      v += __shfl_xor(v, 4, 64);
      v += __shfl_xor(v, 8, 64);
      if ((l & 15) == 0) atomicAdd(&denom[r0 + fr * 16 + r], v);
    }

  // ---- col sums: flush colacc, one atomic per column ----
  __syncthreads();
#pragma unroll
  for (int i = 0; i < 2; ++i) {
    int off = tid + 256 * i;
    float v = colacc[off];
    int col = cs0 + off;
    if (col < NROWS && v != 0.f) atomicAdd(&denom[col], v);
  }
}

// Kernel F: + (1/N) * sum_i (log(denom_i) - posS_{i mod B} * ln2)
__global__ __launch_bounds__(256) void kfin(const float* __restrict__ denom,
                                            const float* __restrict__ pos,
                                            float* __restrict__ out) {
  int i = blockIdx.x * 256 + threadIdx.x;
  float v = (logf(denom[i]) - pos[i & 4095] * LN2) * (1.0f / 8192.0f);
#pragma unroll
  for (int m = 1; m < 64; m <<= 1) v += __shfl_xor(v, m, 64);
  __shared__ float part[4];
  if ((threadIdx.x & 63) == 0) part[threadIdx.x >> 6] = v;
  __syncthreads();
  if (threadIdx.x == 0)
    atomicAdd(out, part[0] + part[1] + part[2] + part[3]);
}

extern "C" void kernel_launch(void* const* d_in, const int* in_sizes, int n_in,
                              void* d_out, int out_size, void* d_ws, size_t ws_size,
                              hipStream_t stream) {
  (void)in_sizes; (void)n_in; (void)out_size; (void)ws_size;
  const float* zi = (const float*)d_in[0];
  const float* zj = (const float*)d_in[1];
  float* out = (float*)d_out;
  char* ws = (char*)d_ws;
  unsigned short* reps = (unsigned short*)ws;                 // 4 MB
  float* denom = (float*)(ws + 4194304);                      // 32 KB
  float* pos   = (float*)(ws + 4194304 + 32768);              // 16 KB

  knorm<<<2048, 256, 0, stream>>>(zi, zj, reps, denom, out);
  ksim<<<NBLK, 256, 0, stream>>>(reps, denom, pos);
  kfin<<<32, 256, 0, stream>>>(denom, pos, out);
}

// Round 11
// 42.454 us; speedup vs baseline: 3.0117x; 1.4806x over previous
//
#include <hip/hip_runtime.h>
#include <hip/hip_bf16.h>
#include <stdint.h>

#define NROWS 8192
#define BROWS 4096
#define LN2 0.6931471805599453f
#define FSC 8.944507e-4f        // (1/T)*log2(e) / 127^2, T=0.1
#define NBLK 544                // sum_{it=0}^{63} ceil((64-it)/4) = 8*68

typedef __attribute__((ext_vector_type(4))) int i32x4;

__device__ inline void gload_lds16(const void* g, void* l) {
  __builtin_amdgcn_global_load_lds((const __attribute__((address_space(1))) void*)g,
                                   (__attribute__((address_space(3))) void*)l,
                                   16, 0, 0);
}

// Kernel A: L2-normalize rows, quantize to i8 (q = rn(127*v/||v||)); zero denom/out.
__global__ __launch_bounds__(256) void knorm(const float* __restrict__ zi,
                                             const float* __restrict__ zj,
                                             int* __restrict__ reps,   // i8 packed, 64 ints/row
                                             float* __restrict__ denom,
                                             float* __restrict__ out) {
  int w = threadIdx.x >> 6, l = threadIdx.x & 63;
  int row = blockIdx.x * 4 + w;
  const float* src = (row < BROWS) ? (zi + (size_t)row * 256)
                                   : (zj + (size_t)(row - BROWS) * 256);
  float4 v = ((const float4*)src)[l];
  float ss = v.x * v.x + v.y * v.y + v.z * v.z + v.w * v.w;
#pragma unroll
  for (int m = 1; m < 64; m <<= 1) ss += __shfl_xor(ss, m, 64);
  float sc = 127.0f / fmaxf(sqrtf(ss), 1e-12f);
  int q0 = __float2int_rn(v.x * sc), q1 = __float2int_rn(v.y * sc);
  int q2 = __float2int_rn(v.z * sc), q3 = __float2int_rn(v.w * sc);
  reps[(size_t)row * 64 + l] =
      (q0 & 255) | ((q1 & 255) << 8) | ((q2 & 255) << 16) | ((q3 & 255) << 24);
  if (l == 0) denom[row] = 0.f;
  if (row == 0 && l == 0) out[0] = 0.f;
}

// Kernel B: upper-tri sim in i8 MFMA (16x16x64). Wave = 32 rows x 64 cols;
// block = 128-row strip x 512-col chunk (544 blocks, XCD-swizzled); 64-col
// dbuf LDS tiles (32KB+2KB -> 4 blocks/CU, 16 waves/CU). Single barrier/iter.
// e = exp2(float(I)*FSC); rowsum in regs, colsum via LDS atomics.
__global__ __launch_bounds__(256, 4) void ksim(const int* __restrict__ reps_,
                                               float* __restrict__ denom,
                                               float* __restrict__ pos) {
  __shared__ uint4 smem[2][1024];    // 2 x 64 reps-rows x 256 B = 32 KB
  __shared__ float colacc[512];      // 2 KB
  int tid = threadIdx.x, w = tid >> 6, l = tid & 63;
  int kgrp = l >> 4;

  // ---- XCD swizzle (544 = 8*68, bijective) + block -> (strip it, chunk q) ----
  int b = blockIdx.x;
  int orig = (b & 7) * 68 + (b >> 3);
  int rem = orig, it = 0, ch;
  while (rem >= (ch = (64 - it + 3) >> 2)) { rem -= ch; ++it; }
  int q = rem;
  int rowbase = it * 128;
  int cs0 = rowbase + q * 512;
  int len = NROWS - cs0; if (len > 512) len = 512;
  int ntile = len >> 6;              // 2,4,6,8

  colacc[tid] = 0.f; colacc[tid + 256] = 0.f;

  // ---- staging: 64 reps-rows x 256B -> 16KB buffer; linear dest, swizzled src.
  //      chunk c2 = 1KB = 4 rows; src kb = ((l&15)*16) ^ ((row&3)<<4) ----
  auto stage = [&](int bufi, int colbase) {
#pragma unroll
    for (int i = 0; i < 4; ++i) {
      int c2 = w * 4 + i;            // 16 chunks of 1 KB
      int lr = c2 * 4 + (l >> 4);    // local row 0..63
      int kb = ((l & 15) * 16) ^ ((lr & 3) << 4);
      gload_lds16((const char*)reps_ + (size_t)(colbase + lr) * 256 + kb,
                  (void*)&smem[bufi][c2 * 64]);
    }
  };
  stage(0, cs0);

  // ---- A fragments: wave w owns rows rowbase+32w..+32; lane holds row
  //      +fr*16+(l&15), bytes [kk*64 + kgrp*16, +16) ----
  i32x4 a[2][4];
  {
    const uint4* r4 = (const uint4*)reps_;
    int arow = rowbase + w * 32 + (l & 15);
#pragma unroll
    for (int fr = 0; fr < 2; ++fr)
#pragma unroll
      for (int kk = 0; kk < 4; ++kk)
        a[fr][kk] = __builtin_bit_cast(i32x4,
            r4[(size_t)(arow + fr * 16) * 16 + kk * 4 + kgrp]);
  }

  // ---- per-kk LDS byte offsets for fc=0 (row = l&15); fc adds +16*256 ----
  int lds_a[4];
  {
    int r0l = l & 15;
    int swz = (r0l & 3) << 4;
#pragma unroll
    for (int kk = 0; kk < 4; ++kk)
      lds_a[kk] = r0l * 256 + ((kk * 64 + kgrp * 16) ^ swz);
  }

  float rowsum[2][4];
#pragma unroll
  for (int fr = 0; fr < 2; ++fr)
#pragma unroll
    for (int r = 0; r < 4; ++r) rowsum[fr][r] = 0.f;

  int r0 = rowbase + w * 32 + kgrp * 4;
  int buf = 0;

  for (int t = 0; t < ntile; ++t) {
    asm volatile("s_waitcnt vmcnt(0)" ::: "memory");   // stage(t), issued 1 iter ago
    __builtin_amdgcn_sched_barrier(0);
    __builtin_amdgcn_s_barrier();      // stage(t) visible; buf^1 reads all done
    __builtin_amdgcn_sched_barrier(0);
    if (t + 1 < ntile) stage(buf ^ 1, cs0 + 64 * (t + 1));

    const char* bb = (const char*)&smem[0][0] + buf * 16384;
    i32x4 acc[2][4];
    const i32x4 zero = {0, 0, 0, 0};
    __builtin_amdgcn_s_setprio(1);
#pragma unroll
    for (int kk = 0; kk < 4; ++kk) {
      i32x4 bf[4];
#pragma unroll
      for (int fc = 0; fc < 4; ++fc)
        bf[fc] = *(const i32x4*)(bb + lds_a[kk] + fc * 4096);
#pragma unroll
      for (int fr = 0; fr < 2; ++fr)
#pragma unroll
        for (int fc = 0; fc < 4; ++fc) {
          if (kk == 0)
            acc[fr][fc] = __builtin_amdgcn_mfma_i32_16x16x64_i8(a[fr][0], bf[fc], zero, 0, 0, 0);
          else
            acc[fr][fc] = __builtin_amdgcn_mfma_i32_16x16x64_i8(a[fr][kk], bf[fc], acc[fr][fc], 0, 0, 0);
        }
    }
    __builtin_amdgcn_s_setprio(0);

    // ---- epilogue: s = I*FSC; e = exp2(s); diag mask; rowsum + col partials ----
    int cb = cs0 + 64 * t;
    bool docol = !(q == 0 && t < 2);        // diag 128-col window: rowsum only
    bool dopos = (q == 8) && (t < 2) && (it < 32);
    float cp[4] = {0.f, 0.f, 0.f, 0.f};
    int cbase = cb + (l & 15);
#pragma unroll
    for (int fr = 0; fr < 2; ++fr)
#pragma unroll
      for (int fc = 0; fc < 4; ++fc)
#pragma unroll
        for (int r = 0; r < 4; ++r) {
          int rg = r0 + fr * 16 + r;
          int cg = cbase + fc * 16;
          float s = (float)acc[fr][fc][r] * FSC;
          float e = __builtin_amdgcn_exp2f(s);
          e = (rg == cg) ? 0.f : e;
          if (dopos && cg == rg + BROWS) pos[rg] = s;
          rowsum[fr][r] += e;
          cp[fc] += e;
        }
    if (docol) {
#pragma unroll
      for (int fc = 0; fc < 4; ++fc) {
        cp[fc] += __shfl_xor(cp[fc], 16, 64);
        cp[fc] += __shfl_xor(cp[fc], 32, 64);
      }
      if (l < 16) {
        int off = (cb - cs0) + l;
#pragma unroll
        for (int fc = 0; fc < 4; ++fc)
          atomicAdd(&colacc[off + fc * 16], cp[fc]);
      }
    }
    buf ^= 1;
  }

  // ---- row sums: reduce 16 col-lanes; 4 lanes atomic per wave ----
#pragma unroll
  for (int fr = 0; fr < 2; ++fr)
#pragma unroll
    for (int r = 0; r < 4; ++r) {
      float v = rowsum[fr][r];
      v += __shfl_xor(v, 1, 64);
      v += __shfl_xor(v, 2, 64);
      v += __shfl_xor(v, 4, 64);
      v += __shfl_xor(v, 8, 64);
      if ((l & 15) == 0) atomicAdd(&denom[r0 + fr * 16 + r], v);
    }

  // ---- col sums: flush colacc, one atomic per column ----
  __syncthreads();
#pragma unroll
  for (int i = 0; i < 2; ++i) {
    int off = tid + 256 * i;
    float v = colacc[off];
    int col = cs0 + off;
    if (col < NROWS && v != 0.f) atomicAdd(&denom[col], v);
  }
}

// Kernel F: + (1/N) * sum_i (log(denom_i) - pos_{i mod B} * ln2)   [pos in log2 units]
__global__ __launch_bounds__(256) void kfin(const float* __restrict__ denom,
                                            const float* __restrict__ pos,
                                            float* __restrict__ out) {
  int i = blockIdx.x * 256 + threadIdx.x;
  float v = (logf(denom[i]) - pos[i & 4095] * LN2) * (1.0f / 8192.0f);
#pragma unroll
  for (int m = 1; m < 64; m <<= 1) v += __shfl_xor(v, m, 64);
  __shared__ float part[4];
  if ((threadIdx.x & 63) == 0) part[threadIdx.x >> 6] = v;
  __syncthreads();
  if (threadIdx.x == 0)
    atomicAdd(out, part[0] + part[1] + part[2] + part[3]);
}

extern "C" void kernel_launch(void* const* d_in, const int* in_sizes, int n_in,
                              void* d_out, int out_size, void* d_ws, size_t ws_size,
                              hipStream_t stream) {
  (void)in_sizes; (void)n_in; (void)out_size; (void)ws_size;
  const float* zi = (const float*)d_in[0];
  const float* zj = (const float*)d_in[1];
  float* out = (float*)d_out;
  char* ws = (char*)d_ws;
  int* reps    = (int*)ws;                                    // 2 MB (i8 packed)
  float* denom = (float*)(ws + 2097152);                      // 32 KB
  float* pos   = (float*)(ws + 2097152 + 32768);              // 16 KB

  knorm<<<2048, 256, 0, stream>>>(zi, zj, reps, denom, out);
  ksim<<<NBLK, 256, 0, stream>>>(reps, denom, pos);
  kfin<<<32, 256, 0, stream>>>(denom, pos, out);
}